// Round 1
// baseline (2782.281 us; speedup 1.0000x reference)
//
#include <hip/hip_runtime.h>
#include <math.h>

#define C_   512
#define C8_  64
#define HH   96
#define WW   96
#define PP   9216            // HH*WW
#define CP   4718592         // C_*PP
#define C8P  589824          // C8_*PP
#define ATTN 1769472         // PP*192

// ---------------- transpose: W (O x C) -> Wt (C x O) ----------------
__global__ __launch_bounds__(256) void transpose_naive(
    const float* __restrict__ in, float* __restrict__ out, int O, int Cc)
{
    int idx = blockIdx.x * 256 + threadIdx.x;
    if (idx >= O * Cc) return;
    int o = idx / Cc, c = idx - o * Cc;
    out[c * O + o] = in[idx];
}

// ---------------- conv1x1: out[b,o,p] = bias[o] + sum_c wt[c,o]*x[b,c,p] ----------------
// grid (PP/64, O/64, g), block 256. Tile 64o x 64p, K-step 16, micro 4x4.
template<int O>
__global__ __launch_bounds__(256) void conv1x1_kernel(
    const float* __restrict__ x, const float* __restrict__ wt,
    const float* __restrict__ bias, float* __restrict__ out)
{
    int p0 = blockIdx.x * 64;
    int o0 = blockIdx.y * 64;
    size_t b = blockIdx.z;
    const float* xb = x + b * (size_t)CP;
    float* outb = out + b * (size_t)O * PP;

    __shared__ __align__(16) float As[16][64];  // [k][o]
    __shared__ __align__(16) float Bs[16][64];  // [k][p]

    int tid = threadIdx.x;
    int lo = tid & 63, lk = tid >> 6;
    int tx = tid & 15, ty = tid >> 4;
    float acc[4][4] = {};

    for (int c0 = 0; c0 < C_; c0 += 16) {
#pragma unroll
        for (int r = 0; r < 4; ++r) {
            As[lk + 4 * r][lo] = wt[(size_t)(c0 + lk + 4 * r) * O + o0 + lo];
            Bs[lk + 4 * r][lo] = xb[(size_t)(c0 + lk + 4 * r) * PP + p0 + lo];
        }
        __syncthreads();
#pragma unroll
        for (int k = 0; k < 16; ++k) {
            float4 a = *(const float4*)(&As[k][ty * 4]);
            float4 bb = *(const float4*)(&Bs[k][tx * 4]);
            float af[4] = {a.x, a.y, a.z, a.w};
            float bf[4] = {bb.x, bb.y, bb.z, bb.w};
#pragma unroll
            for (int i = 0; i < 4; ++i)
#pragma unroll
                for (int j = 0; j < 4; ++j)
                    acc[i][j] = fmaf(af[i], bf[j], acc[i][j]);
        }
        __syncthreads();
    }
#pragma unroll
    for (int i = 0; i < 4; ++i) {
        float bi = bias[o0 + ty * 4 + i];
        float4 r;
        r.x = acc[i][0] + bi; r.y = acc[i][1] + bi;
        r.z = acc[i][2] + bi; r.w = acc[i][3] + bi;
        *(float4*)(&outb[(size_t)(o0 + ty * 4 + i) * PP + p0 + tx * 4]) = r;
    }
}

// ---------------- scoresH: att[b,h,w,j] = sum_c q[b,c,h,w]*k[b,c,j,w], mask j==h ----------------
// grid (WW, g), block 256 (16x16), micro 6x6 strided
__global__ __launch_bounds__(256) void scoresH_kernel(
    const float* __restrict__ q, const float* __restrict__ k, float* __restrict__ att)
{
    int w = blockIdx.x;
    size_t b = blockIdx.y;
    const float* qb = q + b * (size_t)C8P;
    const float* kb = k + b * (size_t)C8P;
    float* attb = att + b * (size_t)ATTN;
    __shared__ float Qs[64][96];
    __shared__ float Ks[64][96];
    for (int idx = threadIdx.x; idx < 64 * 96; idx += 256) {
        int c = idx / 96, h = idx - c * 96;
        size_t gidx = (size_t)c * PP + (size_t)h * 96 + w;
        Qs[c][h] = qb[gidx];
        Ks[c][h] = kb[gidx];
    }
    __syncthreads();
    int tx = threadIdx.x & 15, ty = threadIdx.x >> 4;
    float acc[6][6] = {};
    for (int c = 0; c < 64; ++c) {
        float qf[6], kf[6];
#pragma unroll
        for (int i = 0; i < 6; ++i) { qf[i] = Qs[c][ty + 16 * i]; kf[i] = Ks[c][tx + 16 * i]; }
#pragma unroll
        for (int i = 0; i < 6; ++i)
#pragma unroll
            for (int j = 0; j < 6; ++j) acc[i][j] = fmaf(qf[i], kf[j], acc[i][j]);
    }
#pragma unroll
    for (int i = 0; i < 6; ++i) {
        int h = ty + 16 * i;
#pragma unroll
        for (int j = 0; j < 6; ++j) {
            int jj = tx + 16 * j;
            attb[((size_t)h * 96 + w) * 192 + jj] = (jj == h) ? -INFINITY : acc[i][j];
        }
    }
}

// ---------------- scoresW: att[b,h,w,96+j] = sum_c q[b,c,h,w]*k[b,c,h,j] ----------------
__global__ __launch_bounds__(256) void scoresW_kernel(
    const float* __restrict__ q, const float* __restrict__ k, float* __restrict__ att)
{
    int h = blockIdx.x;
    size_t b = blockIdx.y;
    const float* qb = q + b * (size_t)C8P;
    const float* kb = k + b * (size_t)C8P;
    float* attb = att + b * (size_t)ATTN;
    __shared__ float Qs[64][96];
    __shared__ float Ks[64][96];
    for (int idx = threadIdx.x; idx < 64 * 96; idx += 256) {
        int c = idx / 96, w = idx - c * 96;
        size_t gidx = (size_t)c * PP + (size_t)h * 96 + w;
        Qs[c][w] = qb[gidx];
        Ks[c][w] = kb[gidx];
    }
    __syncthreads();
    int tx = threadIdx.x & 15, ty = threadIdx.x >> 4;
    float acc[6][6] = {};
    for (int c = 0; c < 64; ++c) {
        float qf[6], kf[6];
#pragma unroll
        for (int i = 0; i < 6; ++i) { qf[i] = Qs[c][ty + 16 * i]; kf[i] = Ks[c][tx + 16 * i]; }
#pragma unroll
        for (int i = 0; i < 6; ++i)
#pragma unroll
            for (int j = 0; j < 6; ++j) acc[i][j] = fmaf(qf[i], kf[j], acc[i][j]);
    }
#pragma unroll
    for (int i = 0; i < 6; ++i) {
        int w = ty + 16 * i;
#pragma unroll
        for (int j = 0; j < 6; ++j) {
            int jj = tx + 16 * j;
            attb[((size_t)h * 96 + w) * 192 + 96 + jj] = acc[i][j];
        }
    }
}

// ---------------- softmax over 192, one wave per row ----------------
__global__ __launch_bounds__(256) void softmax192_kernel(float* __restrict__ att, int nrows)
{
    int row = blockIdx.x * 4 + (threadIdx.x >> 6);
    int lane = threadIdx.x & 63;
    if (row >= nrows) return;
    float* r = att + (size_t)row * 192;
    float v0 = r[lane], v1 = r[lane + 64], v2 = r[lane + 128];
    float m = fmaxf(fmaxf(v0, v1), v2);
#pragma unroll
    for (int off = 32; off; off >>= 1) m = fmaxf(m, __shfl_xor(m, off));
    float e0 = __expf(v0 - m), e1 = __expf(v1 - m), e2 = __expf(v2 - m);
    float s = e0 + e1 + e2;
#pragma unroll
    for (int off = 32; off; off >>= 1) s += __shfl_xor(s, off);
    float inv = 1.0f / s;
    r[lane] = e0 * inv; r[lane + 64] = e1 * inv; r[lane + 128] = e2 * inv;
}

// ---------------- applyH: raw[b,c,h,w] = sum_j att[b,h,w,j]*v[b,c,j,w] ----------------
// grid (WW, C_/64, g), block 256 (16x16). c micro 4 (contig via float4), h micro 6 strided.
__global__ __launch_bounds__(256) void applyH_kernel(
    const float* __restrict__ v, const float* __restrict__ att, float* __restrict__ outraw)
{
    int w = blockIdx.x;
    int c0 = blockIdx.y * 64;
    size_t b = blockIdx.z;
    const float* vb = v + b * (size_t)CP;
    const float* attb = att + b * (size_t)ATTN;
    float* ob = outraw + b * (size_t)CP;

    __shared__ __align__(16) float As[32][64];   // [jj][c]
    __shared__ float Ts[96][33];                 // [h][jj] padded
    int tid = threadIdx.x;
    int tx = tid & 15, ty = tid >> 4;
    float acc[4][6] = {};

    for (int j0 = 0; j0 < 96; j0 += 32) {
        {
            int c = tid & 63, jb = tid >> 6;
#pragma unroll
            for (int r = 0; r < 8; ++r) {
                int jj = jb + 4 * r;
                As[jj][c] = vb[(size_t)(c0 + c) * PP + (size_t)(j0 + jj) * 96 + w];
            }
        }
        {
            int jj = tid & 31, hb = tid >> 5;
#pragma unroll
            for (int r = 0; r < 12; ++r) {
                int h = hb + 8 * r;
                Ts[h][jj] = attb[((size_t)h * 96 + w) * 192 + (j0 + jj)];
            }
        }
        __syncthreads();
        for (int jj = 0; jj < 32; ++jj) {
            float4 a = *(const float4*)(&As[jj][ty * 4]);
            float af[4] = {a.x, a.y, a.z, a.w};
            float t[6];
#pragma unroll
            for (int i = 0; i < 6; ++i) t[i] = Ts[tx + 16 * i][jj];
#pragma unroll
            for (int ci = 0; ci < 4; ++ci)
#pragma unroll
                for (int hi = 0; hi < 6; ++hi)
                    acc[ci][hi] = fmaf(af[ci], t[hi], acc[ci][hi]);
        }
        __syncthreads();
    }
#pragma unroll
    for (int ci = 0; ci < 4; ++ci)
#pragma unroll
        for (int hi = 0; hi < 6; ++hi)
            ob[(size_t)(c0 + ty * 4 + ci) * PP + (size_t)(tx + 16 * hi) * 96 + w] = acc[ci][hi];
}

// ---------------- applyW + epilogue: out = g*(raw + sum_j att[...,96+j]*v[b,c,h,j] + 2) + x ----------------
// grid (HH, C_/64, g), block 256.
__global__ __launch_bounds__(256) void applyW_final_kernel(
    const float* __restrict__ v, const float* __restrict__ att,
    const float* __restrict__ x, const float* __restrict__ gamma,
    float* __restrict__ outf)
{
    int h = blockIdx.x;
    int c0 = blockIdx.y * 64;
    size_t b = blockIdx.z;
    const float* vb = v + b * (size_t)CP;
    const float* attb = att + b * (size_t)ATTN;
    const float* xb = x + b * (size_t)CP;
    float* ob = outf + b * (size_t)CP;
    float g = gamma[0];

    __shared__ __align__(16) float As[32][68];   // [jj][c] padded
    __shared__ float Ts[96][33];                 // [w][jj] padded
    int tid = threadIdx.x;
    int tx = tid & 15, ty = tid >> 4;
    float acc[4][6] = {};

    for (int j0 = 0; j0 < 96; j0 += 32) {
        {
            int jj = tid & 31, cb = tid >> 5;
#pragma unroll
            for (int r = 0; r < 8; ++r) {
                int c = cb + 8 * r;
                As[jj][c] = vb[(size_t)(c0 + c) * PP + (size_t)h * 96 + (j0 + jj)];
            }
        }
        {
            int jj = tid & 31, wb = tid >> 5;
#pragma unroll
            for (int r = 0; r < 12; ++r) {
                int w = wb + 8 * r;
                Ts[w][jj] = attb[((size_t)h * 96 + w) * 192 + 96 + (j0 + jj)];
            }
        }
        __syncthreads();
        for (int jj = 0; jj < 32; ++jj) {
            float4 a = *(const float4*)(&As[jj][ty * 4]);
            float af[4] = {a.x, a.y, a.z, a.w};
            float t[6];
#pragma unroll
            for (int i = 0; i < 6; ++i) t[i] = Ts[tx + 16 * i][jj];
#pragma unroll
            for (int ci = 0; ci < 4; ++ci)
#pragma unroll
                for (int wi = 0; wi < 6; ++wi)
                    acc[ci][wi] = fmaf(af[ci], t[wi], acc[ci][wi]);
        }
        __syncthreads();
    }
#pragma unroll
    for (int ci = 0; ci < 4; ++ci) {
        size_t base = (size_t)(c0 + ty * 4 + ci) * PP + (size_t)h * 96;
#pragma unroll
        for (int wi = 0; wi < 6; ++wi) {
            size_t idx = base + tx + 16 * wi;
            float raw = ob[idx];
            ob[idx] = g * (raw + acc[ci][wi] + 2.0f) + xb[idx];
        }
    }
}

extern "C" void kernel_launch(void* const* d_in, const int* in_sizes, int n_in,
                              void* d_out, int out_size, void* d_ws, size_t ws_size,
                              hipStream_t stream)
{
    const float* x_ex = (const float*)d_in[0];
    const float* x_q  = (const float*)d_in[1];
    const float* Wq   = (const float*)d_in[2];
    const float* bq   = (const float*)d_in[3];
    const float* Wk   = (const float*)d_in[4];
    const float* bk   = (const float*)d_in[5];
    const float* Wv   = (const float*)d_in[6];
    const float* bv   = (const float*)d_in[7];
    const float* Wqv  = (const float*)d_in[8];
    const float* bqv  = (const float*)d_in[9];
    const float* g1   = (const float*)d_in[10];
    const float* g2   = (const float*)d_in[11];
    float* out0 = (float*)d_out;
    float* out1 = out0 + (size_t)8 * CP;

    float* ws   = (float*)d_ws;
    float* WvT  = ws;
    float* WqvT = ws + 262144;
    float* WqT  = ws + 524288;
    float* WkT  = ws + 557056;
    float* base = ws + 589824;

    // batch-chunk size based on workspace capacity (deterministic in ws_size)
    int g = 8;
    while (g > 1 && (589824ull + (unsigned long long)g * (ATTN + CP)) * 4ull > (unsigned long long)ws_size)
        g >>= 1;

    float* attb = base;
    float* big  = base + (size_t)g * ATTN;   // v / qv buffer (q,k live here before v)
    float* qb   = big;
    float* kb   = big + (size_t)g * C8P;

    transpose_naive<<<dim3(1024), 256, 0, stream>>>(Wv, WvT, 512, 512);
    transpose_naive<<<dim3(1024), 256, 0, stream>>>(Wqv, WqvT, 512, 512);
    transpose_naive<<<dim3(128), 256, 0, stream>>>(Wq, WqT, 64, 512);
    transpose_naive<<<dim3(128), 256, 0, stream>>>(Wk, WkT, 64, 512);

    for (int b0 = 0; b0 < 8; b0 += g) {
        const float* xe = x_ex + (size_t)b0 * CP;
        const float* xq = x_q  + (size_t)b0 * CP;
        float* o0 = out0 + (size_t)b0 * CP;
        float* o1 = out1 + (size_t)b0 * CP;

        conv1x1_kernel<64><<<dim3(144, 1, g), 256, 0, stream>>>(xq, WqT, bq, qb);
        conv1x1_kernel<64><<<dim3(144, 1, g), 256, 0, stream>>>(xe, WkT, bk, kb);
        scoresH_kernel<<<dim3(WW, g), 256, 0, stream>>>(qb, kb, attb);
        scoresW_kernel<<<dim3(HH, g), 256, 0, stream>>>(qb, kb, attb);
        int rows = g * PP;
        softmax192_kernel<<<dim3(rows / 4), 256, 0, stream>>>(attb, rows);

        conv1x1_kernel<512><<<dim3(144, 8, g), 256, 0, stream>>>(xe, WvT, bv, big);
        applyH_kernel<<<dim3(WW, 8, g), 256, 0, stream>>>(big, attb, o0);
        applyW_final_kernel<<<dim3(HH, 8, g), 256, 0, stream>>>(big, attb, xe, g1, o0);

        conv1x1_kernel<512><<<dim3(144, 8, g), 256, 0, stream>>>(xq, WqvT, bqv, big);
        applyH_kernel<<<dim3(WW, 8, g), 256, 0, stream>>>(big, attb, o1);
        applyW_final_kernel<<<dim3(HH, 8, g), 256, 0, stream>>>(big, attb, xq, g2, o1);
    }
}

// Round 2
// 2217.439 us; speedup vs baseline: 1.2547x; 1.2547x over previous
//
#include <hip/hip_runtime.h>
#include <math.h>

#define C_   512
#define C8_  64
#define HH   96
#define WW   96
#define PP   9216            // HH*WW
#define CP   4718592         // C_*PP
#define C8P  589824          // C8_*PP
#define ATTN 1769472         // PP*192

// ---------------- transpose: W (O x C) -> Wt (C x O) ----------------
__global__ __launch_bounds__(256) void transpose_naive(
    const float* __restrict__ in, float* __restrict__ out, int O, int Cc)
{
    int idx = blockIdx.x * 256 + threadIdx.x;
    if (idx >= O * Cc) return;
    int o = idx / Cc, c = idx - o * Cc;
    out[c * O + o] = in[idx];
}

// ---------------- spatial transpose: out[m,w,h] = in[m,h,w], one 96x96 image per block ----------------
__global__ __launch_bounds__(256) void transpose_hw(
    const float* __restrict__ in, float* __restrict__ out)
{
    size_t m = blockIdx.x;
    const float* im = in + m * (size_t)PP;
    float* om = out + m * (size_t)PP;
    __shared__ float T[96][97];
    for (int idx = threadIdx.x; idx < PP; idx += 256) {
        int r = idx / 96, c = idx - r * 96;
        T[r][c] = im[idx];
    }
    __syncthreads();
    for (int idx = threadIdx.x; idx < PP; idx += 256) {
        int r = idx / 96, c = idx - r * 96;
        om[idx] = T[c][r];
    }
}

// ---------------- conv1x1: out[b,o,p] = bias[o] + sum_c wt[c,o]*x[b,c,p] ----------------
template<int O>
__global__ __launch_bounds__(256) void conv1x1_kernel(
    const float* __restrict__ x, const float* __restrict__ wt,
    const float* __restrict__ bias, float* __restrict__ out)
{
    int p0 = blockIdx.x * 64;
    int o0 = blockIdx.y * 64;
    size_t b = blockIdx.z;
    const float* xb = x + b * (size_t)CP;
    float* outb = out + b * (size_t)O * PP;

    __shared__ __align__(16) float As[16][64];  // [k][o]
    __shared__ __align__(16) float Bs[16][64];  // [k][p]

    int tid = threadIdx.x;
    int lo = tid & 63, lk = tid >> 6;
    int tx = tid & 15, ty = tid >> 4;
    float acc[4][4] = {};

    for (int c0 = 0; c0 < C_; c0 += 16) {
#pragma unroll
        for (int r = 0; r < 4; ++r) {
            As[lk + 4 * r][lo] = wt[(size_t)(c0 + lk + 4 * r) * O + o0 + lo];
            Bs[lk + 4 * r][lo] = xb[(size_t)(c0 + lk + 4 * r) * PP + p0 + lo];
        }
        __syncthreads();
#pragma unroll
        for (int k = 0; k < 16; ++k) {
            float4 a = *(const float4*)(&As[k][ty * 4]);
            float4 bb = *(const float4*)(&Bs[k][tx * 4]);
            float af[4] = {a.x, a.y, a.z, a.w};
            float bf[4] = {bb.x, bb.y, bb.z, bb.w};
#pragma unroll
            for (int i = 0; i < 4; ++i)
#pragma unroll
                for (int j = 0; j < 4; ++j)
                    acc[i][j] = fmaf(af[i], bf[j], acc[i][j]);
        }
        __syncthreads();
    }
#pragma unroll
    for (int i = 0; i < 4; ++i) {
        float bi = bias[o0 + ty * 4 + i];
        float4 r;
        r.x = acc[i][0] + bi; r.y = acc[i][1] + bi;
        r.z = acc[i][2] + bi; r.w = acc[i][3] + bi;
        *(float4*)(&outb[(size_t)(o0 + ty * 4 + i) * PP + p0 + tx * 4]) = r;
    }
}

// ---------------- scoresH (on transposed q,k): att[b,h,w,j] = sum_c qT[b,c,w,h]*kT[b,c,w,j], mask j==h ----------------
// grid (WW, g), block 256 (16x16), micro 6x6 strided. All loads contiguous in last dim.
__global__ __launch_bounds__(256) void scoresHT_kernel(
    const float* __restrict__ qT, const float* __restrict__ kT, float* __restrict__ att)
{
    int w = blockIdx.x;
    size_t b = blockIdx.y;
    const float* qb = qT + b * (size_t)C8P;
    const float* kb = kT + b * (size_t)C8P;
    float* attb = att + b * (size_t)ATTN;
    __shared__ float Qs[64][96];
    __shared__ float Ks[64][96];
    for (int idx = threadIdx.x; idx < 64 * 96; idx += 256) {
        int c = idx / 96, h = idx - c * 96;
        size_t gidx = (size_t)c * PP + (size_t)w * 96 + h;
        Qs[c][h] = qb[gidx];
        Ks[c][h] = kb[gidx];
    }
    __syncthreads();
    int tx = threadIdx.x & 15, ty = threadIdx.x >> 4;
    float acc[6][6] = {};
    for (int c = 0; c < 64; ++c) {
        float qf[6], kf[6];
#pragma unroll
        for (int i = 0; i < 6; ++i) { qf[i] = Qs[c][ty + 16 * i]; kf[i] = Ks[c][tx + 16 * i]; }
#pragma unroll
        for (int i = 0; i < 6; ++i)
#pragma unroll
            for (int j = 0; j < 6; ++j) acc[i][j] = fmaf(qf[i], kf[j], acc[i][j]);
    }
#pragma unroll
    for (int i = 0; i < 6; ++i) {
        int h = ty + 16 * i;
#pragma unroll
        for (int j = 0; j < 6; ++j) {
            int jj = tx + 16 * j;
            attb[((size_t)h * 96 + w) * 192 + jj] = (jj == h) ? -INFINITY : acc[i][j];
        }
    }
}

// ---------------- scoresW: att[b,h,w,96+j] = sum_c q[b,c,h,w]*k[b,c,h,j] ----------------
__global__ __launch_bounds__(256) void scoresW_kernel(
    const float* __restrict__ q, const float* __restrict__ k, float* __restrict__ att)
{
    int h = blockIdx.x;
    size_t b = blockIdx.y;
    const float* qb = q + b * (size_t)C8P;
    const float* kb = k + b * (size_t)C8P;
    float* attb = att + b * (size_t)ATTN;
    __shared__ float Qs[64][96];
    __shared__ float Ks[64][96];
    for (int idx = threadIdx.x; idx < 64 * 96; idx += 256) {
        int c = idx / 96, w = idx - c * 96;
        size_t gidx = (size_t)c * PP + (size_t)h * 96 + w;
        Qs[c][w] = qb[gidx];
        Ks[c][w] = kb[gidx];
    }
    __syncthreads();
    int tx = threadIdx.x & 15, ty = threadIdx.x >> 4;
    float acc[6][6] = {};
    for (int c = 0; c < 64; ++c) {
        float qf[6], kf[6];
#pragma unroll
        for (int i = 0; i < 6; ++i) { qf[i] = Qs[c][ty + 16 * i]; kf[i] = Ks[c][tx + 16 * i]; }
#pragma unroll
        for (int i = 0; i < 6; ++i)
#pragma unroll
            for (int j = 0; j < 6; ++j) acc[i][j] = fmaf(qf[i], kf[j], acc[i][j]);
    }
#pragma unroll
    for (int i = 0; i < 6; ++i) {
        int w = ty + 16 * i;
#pragma unroll
        for (int j = 0; j < 6; ++j) {
            int jj = tx + 16 * j;
            attb[((size_t)h * 96 + w) * 192 + 96 + jj] = acc[i][j];
        }
    }
}

// ---------------- softmax over 192, one wave per row ----------------
__global__ __launch_bounds__(256) void softmax192_kernel(float* __restrict__ att, int nrows)
{
    int row = blockIdx.x * 4 + (threadIdx.x >> 6);
    int lane = threadIdx.x & 63;
    if (row >= nrows) return;
    float* r = att + (size_t)row * 192;
    float v0 = r[lane], v1 = r[lane + 64], v2 = r[lane + 128];
    float m = fmaxf(fmaxf(v0, v1), v2);
#pragma unroll
    for (int off = 32; off; off >>= 1) m = fmaxf(m, __shfl_xor(m, off));
    float e0 = __expf(v0 - m), e1 = __expf(v1 - m), e2 = __expf(v2 - m);
    float s = e0 + e1 + e2;
#pragma unroll
    for (int off = 32; off; off >>= 1) s += __shfl_xor(s, off);
    float inv = 1.0f / s;
    r[lane] = e0 * inv; r[lane + 64] = e1 * inv; r[lane + 128] = e2 * inv;
}

// ---------------- applyHT: rawHT[b,c,w,h] = sum_j att[b,h,w,j]*vT[b,c,w,j] ----------------
// grid (WW, C_/64, g), block 256. Everything contiguous in last dim (h or j).
__global__ __launch_bounds__(256) void applyHT_kernel(
    const float* __restrict__ vT, const float* __restrict__ att, float* __restrict__ rawHT)
{
    int w = blockIdx.x;
    int c0 = blockIdx.y * 64;
    size_t b = blockIdx.z;
    const float* vb = vT + b * (size_t)CP;
    const float* attb = att + b * (size_t)ATTN;
    float* ob = rawHT + b * (size_t)CP;

    __shared__ __align__(16) float As[32][68];   // [jj][c] padded
    __shared__ float Ts[96][33];                 // [h][jj] padded
    int tid = threadIdx.x;
    int tx = tid & 15, ty = tid >> 4;
    float acc[4][6] = {};

    for (int j0 = 0; j0 < 96; j0 += 32) {
        {
            int jj = tid & 31, cb = tid >> 5;
#pragma unroll
            for (int r = 0; r < 8; ++r) {
                int c = cb + 8 * r;
                As[jj][c] = vb[(size_t)(c0 + c) * PP + (size_t)w * 96 + (j0 + jj)];
            }
        }
        {
            int jj = tid & 31, hb = tid >> 5;
#pragma unroll
            for (int r = 0; r < 12; ++r) {
                int h = hb + 8 * r;
                Ts[h][jj] = attb[((size_t)h * 96 + w) * 192 + (j0 + jj)];
            }
        }
        __syncthreads();
        for (int jj = 0; jj < 32; ++jj) {
            float4 a = *(const float4*)(&As[jj][ty * 4]);
            float af[4] = {a.x, a.y, a.z, a.w};
            float t[6];
#pragma unroll
            for (int i = 0; i < 6; ++i) t[i] = Ts[tx + 16 * i][jj];
#pragma unroll
            for (int ci = 0; ci < 4; ++ci)
#pragma unroll
                for (int hi = 0; hi < 6; ++hi)
                    acc[ci][hi] = fmaf(af[ci], t[hi], acc[ci][hi]);
        }
        __syncthreads();
    }
#pragma unroll
    for (int ci = 0; ci < 4; ++ci) {
        size_t base = (size_t)(c0 + ty * 4 + ci) * PP + (size_t)w * 96;
#pragma unroll
        for (int hi = 0; hi < 6; ++hi)
            ob[base + tx + 16 * hi] = acc[ci][hi];
    }
}

// ---------------- applyW: rawW[b,c,h,w] = sum_j att[b,h,w,96+j]*v[b,c,h,j] ----------------
__global__ __launch_bounds__(256) void applyW_kernel(
    const float* __restrict__ v, const float* __restrict__ att, float* __restrict__ rawW)
{
    int h = blockIdx.x;
    int c0 = blockIdx.y * 64;
    size_t b = blockIdx.z;
    const float* vb = v + b * (size_t)CP;
    const float* attb = att + b * (size_t)ATTN;
    float* ob = rawW + b * (size_t)CP;

    __shared__ __align__(16) float As[32][68];   // [jj][c] padded
    __shared__ float Ts[96][33];                 // [w][jj] padded
    int tid = threadIdx.x;
    int tx = tid & 15, ty = tid >> 4;
    float acc[4][6] = {};

    for (int j0 = 0; j0 < 96; j0 += 32) {
        {
            int jj = tid & 31, cb = tid >> 5;
#pragma unroll
            for (int r = 0; r < 8; ++r) {
                int c = cb + 8 * r;
                As[jj][c] = vb[(size_t)(c0 + c) * PP + (size_t)h * 96 + (j0 + jj)];
            }
        }
        {
            int jj = tid & 31, wb = tid >> 5;
#pragma unroll
            for (int r = 0; r < 12; ++r) {
                int w = wb + 8 * r;
                Ts[w][jj] = attb[((size_t)h * 96 + w) * 192 + 96 + (j0 + jj)];
            }
        }
        __syncthreads();
        for (int jj = 0; jj < 32; ++jj) {
            float4 a = *(const float4*)(&As[jj][ty * 4]);
            float af[4] = {a.x, a.y, a.z, a.w};
            float t[6];
#pragma unroll
            for (int i = 0; i < 6; ++i) t[i] = Ts[tx + 16 * i][jj];
#pragma unroll
            for (int ci = 0; ci < 4; ++ci)
#pragma unroll
                for (int wi = 0; wi < 6; ++wi)
                    acc[ci][wi] = fmaf(af[ci], t[wi], acc[ci][wi]);
        }
        __syncthreads();
    }
#pragma unroll
    for (int ci = 0; ci < 4; ++ci) {
        size_t base = (size_t)(c0 + ty * 4 + ci) * PP + (size_t)h * 96;
#pragma unroll
        for (int wi = 0; wi < 6; ++wi)
            ob[base + tx + 16 * wi] = acc[ci][wi];
    }
}

// ---------------- combine: out[c,h,w] = g*(rawHT[c,w,h] + rawW[c,h,w] + 2) + x[c,h,w] ----------------
// one 96x96 image (one c of one b) per block, LDS transpose of rawHT
__global__ __launch_bounds__(256) void combine_kernel(
    const float* __restrict__ rawHT, const float* __restrict__ rawW,
    const float* __restrict__ x, const float* __restrict__ gamma,
    float* __restrict__ out)
{
    size_t m = blockIdx.x;
    const float* a  = rawHT + m * (size_t)PP;
    const float* bw = rawW  + m * (size_t)PP;
    const float* xm = x     + m * (size_t)PP;
    float* om = out + m * (size_t)PP;
    float g = gamma[0];
    __shared__ float T[96][97];
    for (int idx = threadIdx.x; idx < PP; idx += 256) {
        int r = idx / 96, c = idx - r * 96;
        T[r][c] = a[idx];
    }
    __syncthreads();
    for (int idx = threadIdx.x; idx < PP; idx += 256) {
        int r = idx / 96, c = idx - r * 96;   // r = h, c = w
        om[idx] = g * (T[c][r] + bw[idx] + 2.0f) + xm[idx];
    }
}

extern "C" void kernel_launch(void* const* d_in, const int* in_sizes, int n_in,
                              void* d_out, int out_size, void* d_ws, size_t ws_size,
                              hipStream_t stream)
{
    const float* x_ex = (const float*)d_in[0];
    const float* x_q  = (const float*)d_in[1];
    const float* Wq   = (const float*)d_in[2];
    const float* bq   = (const float*)d_in[3];
    const float* Wk   = (const float*)d_in[4];
    const float* bk   = (const float*)d_in[5];
    const float* Wv   = (const float*)d_in[6];
    const float* bv   = (const float*)d_in[7];
    const float* Wqv  = (const float*)d_in[8];
    const float* bqv  = (const float*)d_in[9];
    const float* g1   = (const float*)d_in[10];
    const float* g2   = (const float*)d_in[11];
    float* out0 = (float*)d_out;
    float* out1 = out0 + (size_t)8 * CP;

    float* ws   = (float*)d_ws;
    float* WvT  = ws;
    float* WqvT = ws + 262144;
    float* WqT  = ws + 524288;
    float* WkT  = ws + 557056;
    float* base = ws + 589824;

    // batch-chunk size based on workspace capacity (deterministic in ws_size)
    int g = 8;
    while (g > 1 && (589824ull + (unsigned long long)g * ((unsigned long long)ATTN + 4ull * CP)) * 4ull > (unsigned long long)ws_size)
        g >>= 1;

    float* attb = base;
    float* buf1 = attb + (size_t)g * ATTN;  // v / (q,k,qT,kT staging)
    float* buf2 = buf1 + (size_t)g * CP;    // vT
    float* buf3 = buf2 + (size_t)g * CP;    // rawHT
    float* buf4 = buf3 + (size_t)g * CP;    // rawW
    float* qb   = buf1;
    float* kb   = buf1 + (size_t)g * C8P;
    float* qTb  = buf1 + 2 * (size_t)g * C8P;
    float* kTb  = buf1 + 3 * (size_t)g * C8P;

    transpose_naive<<<dim3(1024), 256, 0, stream>>>(Wv, WvT, 512, 512);
    transpose_naive<<<dim3(1024), 256, 0, stream>>>(Wqv, WqvT, 512, 512);
    transpose_naive<<<dim3(128), 256, 0, stream>>>(Wq, WqT, 64, 512);
    transpose_naive<<<dim3(128), 256, 0, stream>>>(Wk, WkT, 64, 512);

    for (int b0 = 0; b0 < 8; b0 += g) {
        const float* xe = x_ex + (size_t)b0 * CP;
        const float* xq = x_q  + (size_t)b0 * CP;
        float* o0 = out0 + (size_t)b0 * CP;
        float* o1 = out1 + (size_t)b0 * CP;

        // q, k (64 ch) + spatial transposes
        conv1x1_kernel<64><<<dim3(144, 1, g), 256, 0, stream>>>(xq, WqT, bq, qb);
        conv1x1_kernel<64><<<dim3(144, 1, g), 256, 0, stream>>>(xe, WkT, bk, kb);
        transpose_hw<<<dim3(g * 64), 256, 0, stream>>>(qb, qTb);
        transpose_hw<<<dim3(g * 64), 256, 0, stream>>>(kb, kTb);

        // scores + softmax
        scoresHT_kernel<<<dim3(WW, g), 256, 0, stream>>>(qTb, kTb, attb);
        scoresW_kernel<<<dim3(HH, g), 256, 0, stream>>>(qb, kb, attb);
        int rows = g * PP;
        softmax192_kernel<<<dim3(rows / 4), 256, 0, stream>>>(attb, rows);

        // examplar path: v = conv(x_ex, Wv)
        conv1x1_kernel<512><<<dim3(144, 8, g), 256, 0, stream>>>(xe, WvT, bv, buf1);
        transpose_hw<<<dim3(g * 512), 256, 0, stream>>>(buf1, buf2);
        applyHT_kernel<<<dim3(WW, 8, g), 256, 0, stream>>>(buf2, attb, buf3);
        applyW_kernel<<<dim3(HH, 8, g), 256, 0, stream>>>(buf1, attb, buf4);
        combine_kernel<<<dim3(g * 512), 256, 0, stream>>>(buf3, buf4, xe, g1, o0);

        // query path: qv = conv(x_q, Wqv)
        conv1x1_kernel<512><<<dim3(144, 8, g), 256, 0, stream>>>(xq, WqvT, bqv, buf1);
        transpose_hw<<<dim3(g * 512), 256, 0, stream>>>(buf1, buf2);
        applyHT_kernel<<<dim3(WW, 8, g), 256, 0, stream>>>(buf2, attb, buf3);
        applyW_kernel<<<dim3(HH, 8, g), 256, 0, stream>>>(buf1, attb, buf4);
        combine_kernel<<<dim3(g * 512), 256, 0, stream>>>(buf3, buf4, xq, g2, o1);
    }
}

// Round 3
// 1086.630 us; speedup vs baseline: 2.5605x; 2.0407x over previous
//
#include <hip/hip_runtime.h>
#include <math.h>

#define C_   512
#define C8_  64
#define HH   96
#define WW   96
#define PP   9216            // HH*WW
#define CP   4718592         // C_*PP
#define C8P  589824          // C8_*PP
#define ATTN 1769472         // PP*192

typedef __attribute__((ext_vector_type(4))) float f32x4;
typedef __attribute__((ext_vector_type(8))) __bf16 bf16x8;

__device__ __forceinline__ float bf2f(unsigned short u) {
    union { unsigned u; float f; } x; x.u = ((unsigned)u) << 16; return x.f;
}
__device__ __forceinline__ unsigned short f2bf(float f) {
    union { float f; unsigned u; } x; x.f = f;
    unsigned r = x.u + 0x7fffu + ((x.u >> 16) & 1u);
    return (unsigned short)(r >> 16);
}
__device__ __forceinline__ void gload16(const void* g, void* l) {
    __builtin_amdgcn_global_load_lds(
        (const __attribute__((address_space(1))) unsigned int*)g,
        (__attribute__((address_space(3))) unsigned int*)l, 16, 0, 0);
}

// ---------------- weight cast fp32 -> bf16 (layout [O][C] kept) ----------------
__global__ __launch_bounds__(256) void cast_f32_bf16(
    const float* __restrict__ in, unsigned short* __restrict__ out, int n)
{
    int i = blockIdx.x * 256 + threadIdx.x;
    if (i < n) out[i] = f2bf(in[i]);
}

// ---------------- x [b][C][P] fp32 -> xT [b][P][C] bf16 ----------------
// grid (PP/64, C/64, g)
__global__ __launch_bounds__(256) void cast_transpose_cp(
    const float* __restrict__ x, unsigned short* __restrict__ xT)
{
    int p0 = blockIdx.x * 64, c0 = blockIdx.y * 64;
    size_t b = blockIdx.z;
    const float* xb = x + b * (size_t)CP;
    unsigned short* xTb = xT + b * (size_t)CP;
    __shared__ unsigned short T[64][65];
    int tid = threadIdx.x;
#pragma unroll
    for (int i = 0; i < 16; ++i) {
        int e = tid + 256 * i;
        int r = e >> 6, c = e & 63;          // r: channel offset, c: pixel offset
        T[r][c] = f2bf(xb[(size_t)(c0 + r) * PP + p0 + c]);
    }
    __syncthreads();
#pragma unroll
    for (int i = 0; i < 16; ++i) {
        int e = tid + 256 * i;
        int pr = e >> 6, cc = e & 63;
        xTb[(size_t)(p0 + pr) * C_ + c0 + cc] = T[cc][pr];
    }
}

// ---------------- MFMA GEMM: out[b,o,p] = bias[o] + sum_k W[o,k]*xT[b,p,k] ----------------
// A = W bf16 [O][512]; B = xT bf16 [b][P][512]; grid (PP/128, O/BM, g), 256 thr (4 waves 2x2).
template<int BM, bool OUT_BF16>
__global__ __launch_bounds__(256) void gemm_conv(
    const unsigned short* __restrict__ A, const unsigned short* __restrict__ Bmat,
    const float* __restrict__ bias, void* __restrict__ outv, int OPP)
{
    constexpr int FM = BM / 32;
    int p0 = blockIdx.x * 128;
    int o0 = blockIdx.y * BM;
    size_t b = blockIdx.z;
    const unsigned short* Bb = Bmat + b * (size_t)CP;

    __shared__ __align__(16) unsigned short Asm[BM * 32];
    __shared__ __align__(16) unsigned short Bsm[128 * 32];

    int tid = threadIdx.x;
    int lane = tid & 63, wid = tid >> 6;
    int wr = wid >> 1, wc = wid & 1;
    int l15 = lane & 15, l4 = lane >> 4;

    f32x4 acc[FM][4] = {};

    for (int k0 = 0; k0 < 512; k0 += 32) {
        {
            int c = tid;
            gload16(A + (size_t)(o0 + (c >> 2)) * 512 + k0 + (c & 3) * 8, Asm + c * 8);
            if constexpr (BM == 128) {
                int ca = tid + 256;
                gload16(A + (size_t)(o0 + (ca >> 2)) * 512 + k0 + (ca & 3) * 8, Asm + ca * 8);
            }
            gload16(Bb + (size_t)(p0 + (c >> 2)) * 512 + k0 + (c & 3) * 8, Bsm + c * 8);
            int cb = tid + 256;
            gload16(Bb + (size_t)(p0 + (cb >> 2)) * 512 + k0 + (cb & 3) * 8, Bsm + cb * 8);
        }
        __syncthreads();
        bf16x8 af[FM], bfr[4];
#pragma unroll
        for (int m = 0; m < FM; ++m)
            af[m] = *(const bf16x8*)&Asm[(wr * (BM / 2) + m * 16 + l15) * 32 + l4 * 8];
#pragma unroll
        for (int n = 0; n < 4; ++n)
            bfr[n] = *(const bf16x8*)&Bsm[(wc * 64 + n * 16 + l15) * 32 + l4 * 8];
#pragma unroll
        for (int m = 0; m < FM; ++m)
#pragma unroll
            for (int n = 0; n < 4; ++n)
                acc[m][n] = __builtin_amdgcn_mfma_f32_16x16x32_bf16(af[m], bfr[n], acc[m][n], 0, 0, 0);
        __syncthreads();
    }

#pragma unroll
    for (int m = 0; m < FM; ++m) {
#pragma unroll
        for (int n = 0; n < 4; ++n) {
            int pcol = p0 + wc * 64 + n * 16 + l15;
#pragma unroll
            for (int r = 0; r < 4; ++r) {
                int orow = o0 + wr * (BM / 2) + m * 16 + l4 * 4 + r;
                float val = acc[m][n][r] + bias[orow];
                if constexpr (OUT_BF16)
                    ((unsigned short*)outv)[b * (size_t)OPP + (size_t)orow * PP + pcol] = f2bf(val);
                else
                    ((float*)outv)[b * (size_t)OPP + (size_t)orow * PP + pcol] = val;
            }
        }
    }
}

// ---------------- spatial transpose fp32: out[m,w,h] = in[m,h,w] ----------------
__global__ __launch_bounds__(256) void transpose_hw(
    const float* __restrict__ in, float* __restrict__ out)
{
    size_t m = blockIdx.x;
    const float* im = in + m * (size_t)PP;
    float* om = out + m * (size_t)PP;
    __shared__ float T[96][97];
    for (int idx = threadIdx.x; idx < PP; idx += 256) {
        int r = idx / 96, c = idx - r * 96;
        T[r][c] = im[idx];
    }
    __syncthreads();
    for (int idx = threadIdx.x; idx < PP; idx += 256) {
        int r = idx / 96, c = idx - r * 96;
        om[idx] = T[c][r];
    }
}

// ---------------- spatial transpose bf16 ----------------
__global__ __launch_bounds__(256) void transpose_hw_b(
    const unsigned short* __restrict__ in, unsigned short* __restrict__ out)
{
    size_t m = blockIdx.x;
    const unsigned short* im = in + m * (size_t)PP;
    unsigned short* om = out + m * (size_t)PP;
    __shared__ unsigned short T[96][97];
    for (int idx = threadIdx.x; idx < PP; idx += 256) {
        int r = idx / 96, c = idx - r * 96;
        T[r][c] = im[idx];
    }
    __syncthreads();
    for (int idx = threadIdx.x; idx < PP; idx += 256) {
        int r = idx / 96, c = idx - r * 96;
        om[idx] = T[c][r];
    }
}

// ---------------- scoresH (on transposed q,k): att[b,h,w,j] = sum_c qT[c,w,h]*kT[c,w,j], mask j==h ----------------
__global__ __launch_bounds__(256) void scoresHT_kernel(
    const float* __restrict__ qT, const float* __restrict__ kT, float* __restrict__ att)
{
    int w = blockIdx.x;
    size_t b = blockIdx.y;
    const float* qb = qT + b * (size_t)C8P;
    const float* kb = kT + b * (size_t)C8P;
    float* attb = att + b * (size_t)ATTN;
    __shared__ float Qs[64][96];
    __shared__ float Ks[64][96];
    for (int idx = threadIdx.x; idx < 64 * 96; idx += 256) {
        int c = idx / 96, h = idx - c * 96;
        size_t gidx = (size_t)c * PP + (size_t)w * 96 + h;
        Qs[c][h] = qb[gidx];
        Ks[c][h] = kb[gidx];
    }
    __syncthreads();
    int tx = threadIdx.x & 15, ty = threadIdx.x >> 4;
    float acc[6][6] = {};
    for (int c = 0; c < 64; ++c) {
        float qf[6], kf[6];
#pragma unroll
        for (int i = 0; i < 6; ++i) { qf[i] = Qs[c][ty + 16 * i]; kf[i] = Ks[c][tx + 16 * i]; }
#pragma unroll
        for (int i = 0; i < 6; ++i)
#pragma unroll
            for (int j = 0; j < 6; ++j) acc[i][j] = fmaf(qf[i], kf[j], acc[i][j]);
    }
#pragma unroll
    for (int i = 0; i < 6; ++i) {
        int h = ty + 16 * i;
#pragma unroll
        for (int j = 0; j < 6; ++j) {
            int jj = tx + 16 * j;
            attb[((size_t)h * 96 + w) * 192 + jj] = (jj == h) ? -INFINITY : acc[i][j];
        }
    }
}

// ---------------- scoresW: att[b,h,w,96+j] = sum_c q[c,h,w]*k[c,h,j] ----------------
__global__ __launch_bounds__(256) void scoresW_kernel(
    const float* __restrict__ q, const float* __restrict__ k, float* __restrict__ att)
{
    int h = blockIdx.x;
    size_t b = blockIdx.y;
    const float* qb = q + b * (size_t)C8P;
    const float* kb = k + b * (size_t)C8P;
    float* attb = att + b * (size_t)ATTN;
    __shared__ float Qs[64][96];
    __shared__ float Ks[64][96];
    for (int idx = threadIdx.x; idx < 64 * 96; idx += 256) {
        int c = idx / 96, w = idx - c * 96;
        size_t gidx = (size_t)c * PP + (size_t)h * 96 + w;
        Qs[c][w] = qb[gidx];
        Ks[c][w] = kb[gidx];
    }
    __syncthreads();
    int tx = threadIdx.x & 15, ty = threadIdx.x >> 4;
    float acc[6][6] = {};
    for (int c = 0; c < 64; ++c) {
        float qf[6], kf[6];
#pragma unroll
        for (int i = 0; i < 6; ++i) { qf[i] = Qs[c][ty + 16 * i]; kf[i] = Ks[c][tx + 16 * i]; }
#pragma unroll
        for (int i = 0; i < 6; ++i)
#pragma unroll
            for (int j = 0; j < 6; ++j) acc[i][j] = fmaf(qf[i], kf[j], acc[i][j]);
    }
#pragma unroll
    for (int i = 0; i < 6; ++i) {
        int w = ty + 16 * i;
#pragma unroll
        for (int j = 0; j < 6; ++j) {
            int jj = tx + 16 * j;
            attb[((size_t)h * 96 + w) * 192 + 96 + jj] = acc[i][j];
        }
    }
}

// ---------------- softmax over 192 fp32 -> bf16 probs ----------------
__global__ __launch_bounds__(256) void softmax192_kernel(
    const float* __restrict__ att, unsigned short* __restrict__ attb, int nrows)
{
    int row = blockIdx.x * 4 + (threadIdx.x >> 6);
    int lane = threadIdx.x & 63;
    if (row >= nrows) return;
    const float* r = att + (size_t)row * 192;
    unsigned short* o = attb + (size_t)row * 192;
    float v0 = r[lane], v1 = r[lane + 64], v2 = r[lane + 128];
    float m = fmaxf(fmaxf(v0, v1), v2);
#pragma unroll
    for (int off = 32; off; off >>= 1) m = fmaxf(m, __shfl_xor(m, off));
    float e0 = __expf(v0 - m), e1 = __expf(v1 - m), e2 = __expf(v2 - m);
    float s = e0 + e1 + e2;
#pragma unroll
    for (int off = 32; off; off >>= 1) s += __shfl_xor(s, off);
    float inv = 1.0f / s;
    o[lane] = f2bf(e0 * inv); o[lane + 64] = f2bf(e1 * inv); o[lane + 128] = f2bf(e2 * inv);
}

// ---------------- applyHT: rawHT[b,c,w,h] = sum_j att[b,h,w,j]*vT[b,c,w,j] (all bf16 I/O) ----------------
__global__ __launch_bounds__(256) void applyHT_b(
    const unsigned short* __restrict__ vT, const unsigned short* __restrict__ att,
    unsigned short* __restrict__ rawHT)
{
    int w = blockIdx.x;
    int c0 = blockIdx.y * 64;
    size_t b = blockIdx.z;
    const unsigned short* vb = vT + b * (size_t)CP;
    const unsigned short* attb = att + b * (size_t)ATTN;
    unsigned short* ob = rawHT + b * (size_t)CP;

    __shared__ float As[32][68];
    __shared__ float Ts[96][33];
    int tid = threadIdx.x;
    int tx = tid & 15, ty = tid >> 4;
    float acc[4][6] = {};

    for (int j0 = 0; j0 < 96; j0 += 32) {
        {
            int jj = tid & 31, cb = tid >> 5;
#pragma unroll
            for (int r = 0; r < 8; ++r) {
                int c = cb + 8 * r;
                As[jj][c] = bf2f(vb[(size_t)(c0 + c) * PP + (size_t)w * 96 + (j0 + jj)]);
            }
        }
        {
            int jj = tid & 31, hb = tid >> 5;
#pragma unroll
            for (int r = 0; r < 12; ++r) {
                int h = hb + 8 * r;
                Ts[h][jj] = bf2f(attb[((size_t)h * 96 + w) * 192 + (j0 + jj)]);
            }
        }
        __syncthreads();
        for (int jj = 0; jj < 32; ++jj) {
            float4 a4 = *(const float4*)(&As[jj][ty * 4]);
            float af[4] = {a4.x, a4.y, a4.z, a4.w};
            float t[6];
#pragma unroll
            for (int i = 0; i < 6; ++i) t[i] = Ts[tx + 16 * i][jj];
#pragma unroll
            for (int ci = 0; ci < 4; ++ci)
#pragma unroll
                for (int hi = 0; hi < 6; ++hi)
                    acc[ci][hi] = fmaf(af[ci], t[hi], acc[ci][hi]);
        }
        __syncthreads();
    }
#pragma unroll
    for (int ci = 0; ci < 4; ++ci) {
        size_t base = (size_t)(c0 + ty * 4 + ci) * PP + (size_t)w * 96;
#pragma unroll
        for (int hi = 0; hi < 6; ++hi)
            ob[base + tx + 16 * hi] = f2bf(acc[ci][hi]);
    }
}

// ---------------- applyW: rawW[b,c,h,w] = sum_j att[b,h,w,96+j]*v[b,c,h,j] (all bf16 I/O) ----------------
__global__ __launch_bounds__(256) void applyW_b(
    const unsigned short* __restrict__ v, const unsigned short* __restrict__ att,
    unsigned short* __restrict__ rawW)
{
    int h = blockIdx.x;
    int c0 = blockIdx.y * 64;
    size_t b = blockIdx.z;
    const unsigned short* vb = v + b * (size_t)CP;
    const unsigned short* attb = att + b * (size_t)ATTN;
    unsigned short* ob = rawW + b * (size_t)CP;

    __shared__ float As[32][68];
    __shared__ float Ts[96][33];
    int tid = threadIdx.x;
    int tx = tid & 15, ty = tid >> 4;
    float acc[4][6] = {};

    for (int j0 = 0; j0 < 96; j0 += 32) {
        {
            int jj = tid & 31, cb = tid >> 5;
#pragma unroll
            for (int r = 0; r < 8; ++r) {
                int c = cb + 8 * r;
                As[jj][c] = bf2f(vb[(size_t)(c0 + c) * PP + (size_t)h * 96 + (j0 + jj)]);
            }
        }
        {
            int jj = tid & 31, wb = tid >> 5;
#pragma unroll
            for (int r = 0; r < 12; ++r) {
                int w = wb + 8 * r;
                Ts[w][jj] = bf2f(attb[((size_t)h * 96 + w) * 192 + 96 + (j0 + jj)]);
            }
        }
        __syncthreads();
        for (int jj = 0; jj < 32; ++jj) {
            float4 a4 = *(const float4*)(&As[jj][ty * 4]);
            float af[4] = {a4.x, a4.y, a4.z, a4.w};
            float t[6];
#pragma unroll
            for (int i = 0; i < 6; ++i) t[i] = Ts[tx + 16 * i][jj];
#pragma unroll
            for (int ci = 0; ci < 4; ++ci)
#pragma unroll
                for (int wi = 0; wi < 6; ++wi)
                    acc[ci][wi] = fmaf(af[ci], t[wi], acc[ci][wi]);
        }
        __syncthreads();
    }
#pragma unroll
    for (int ci = 0; ci < 4; ++ci) {
        size_t base = (size_t)(c0 + ty * 4 + ci) * PP + (size_t)h * 96;
#pragma unroll
        for (int wi = 0; wi < 6; ++wi)
            ob[base + tx + 16 * wi] = f2bf(acc[ci][wi]);
    }
}

// ---------------- combine: out[c,h,w] = g*(rawHT[c,w,h] + rawW[c,h,w] + 2) + x[c,h,w] ----------------
__global__ __launch_bounds__(256) void combine_b(
    const unsigned short* __restrict__ rawHT, const unsigned short* __restrict__ rawW,
    const float* __restrict__ x, const float* __restrict__ gamma,
    float* __restrict__ out)
{
    size_t m = blockIdx.x;
    const unsigned short* a  = rawHT + m * (size_t)PP;
    const unsigned short* bw = rawW  + m * (size_t)PP;
    const float* xm = x + m * (size_t)PP;
    float* om = out + m * (size_t)PP;
    float g = gamma[0];
    __shared__ float T[96][97];
    for (int idx = threadIdx.x; idx < PP; idx += 256) {
        int r = idx / 96, c = idx - r * 96;
        T[r][c] = bf2f(a[idx]);
    }
    __syncthreads();
    for (int idx = threadIdx.x; idx < PP; idx += 256) {
        int r = idx / 96, c = idx - r * 96;   // r = h, c = w
        om[idx] = g * (T[c][r] + bf2f(bw[idx]) + 2.0f) + xm[idx];
    }
}

extern "C" void kernel_launch(void* const* d_in, const int* in_sizes, int n_in,
                              void* d_out, int out_size, void* d_ws, size_t ws_size,
                              hipStream_t stream)
{
    const float* x_ex = (const float*)d_in[0];
    const float* x_q  = (const float*)d_in[1];
    const float* Wq   = (const float*)d_in[2];
    const float* bq   = (const float*)d_in[3];
    const float* Wk   = (const float*)d_in[4];
    const float* bk   = (const float*)d_in[5];
    const float* Wv   = (const float*)d_in[6];
    const float* bv   = (const float*)d_in[7];
    const float* Wqv  = (const float*)d_in[8];
    const float* bqv  = (const float*)d_in[9];
    const float* g1   = (const float*)d_in[10];
    const float* g2   = (const float*)d_in[11];
    float* out0 = (float*)d_out;
    float* out1 = out0 + (size_t)8 * CP;

    char* p = (char*)d_ws;
    unsigned short* Wvb  = (unsigned short*)p; p += (size_t)262144 * 2;
    unsigned short* Wqvb = (unsigned short*)p; p += (size_t)262144 * 2;
    unsigned short* Wqb  = (unsigned short*)p; p += (size_t)32768 * 2;
    unsigned short* Wkb  = (unsigned short*)p; p += (size_t)32768 * 2;

    // per-batch-chunk bytes: attf(f32) + attb(bf16) + 6 CP-sized bf16 + 4 C8P f32
    size_t per = (size_t)ATTN * 4 + (size_t)ATTN * 2 + 6ull * CP * 2 + 4ull * C8P * 4;
    size_t head = (size_t)(p - (char*)d_ws);
    int g = 8;
    while (g > 1 && head + (size_t)g * per > ws_size) g >>= 1;

    char* q = p;
    float*          attf = (float*)q;          q += (size_t)g * ATTN * 4;
    unsigned short* attb = (unsigned short*)q; q += (size_t)g * ATTN * 2;
    unsigned short* xTe  = (unsigned short*)q; q += (size_t)g * CP * 2;
    unsigned short* xTq  = (unsigned short*)q; q += (size_t)g * CP * 2;
    unsigned short* vbuf = (unsigned short*)q; q += (size_t)g * CP * 2;
    unsigned short* vTb  = (unsigned short*)q; q += (size_t)g * CP * 2;
    unsigned short* raw1 = (unsigned short*)q; q += (size_t)g * CP * 2;
    unsigned short* raw2 = (unsigned short*)q; q += (size_t)g * CP * 2;
    float* qbuf  = (float*)q; q += (size_t)g * C8P * 4;
    float* kbuf  = (float*)q; q += (size_t)g * C8P * 4;
    float* qTbuf = (float*)q; q += (size_t)g * C8P * 4;
    float* kTbuf = (float*)q; q += (size_t)g * C8P * 4;

    cast_f32_bf16<<<dim3(1024), 256, 0, stream>>>(Wv,  Wvb,  262144);
    cast_f32_bf16<<<dim3(1024), 256, 0, stream>>>(Wqv, Wqvb, 262144);
    cast_f32_bf16<<<dim3(128),  256, 0, stream>>>(Wq,  Wqb,  32768);
    cast_f32_bf16<<<dim3(128),  256, 0, stream>>>(Wk,  Wkb,  32768);

    for (int b0 = 0; b0 < 8; b0 += g) {
        const float* xe = x_ex + (size_t)b0 * CP;
        const float* xq = x_q  + (size_t)b0 * CP;
        float* o0 = out0 + (size_t)b0 * CP;
        float* o1 = out1 + (size_t)b0 * CP;

        cast_transpose_cp<<<dim3(144, 8, g), 256, 0, stream>>>(xq, xTq);
        cast_transpose_cp<<<dim3(144, 8, g), 256, 0, stream>>>(xe, xTe);

        gemm_conv<64, false><<<dim3(72, 1, g), 256, 0, stream>>>(Wqb, xTq, bq, qbuf, C8P);
        gemm_conv<64, false><<<dim3(72, 1, g), 256, 0, stream>>>(Wkb, xTe, bk, kbuf, C8P);
        transpose_hw<<<dim3(g * 64), 256, 0, stream>>>(qbuf, qTbuf);
        transpose_hw<<<dim3(g * 64), 256, 0, stream>>>(kbuf, kTbuf);

        scoresHT_kernel<<<dim3(WW, g), 256, 0, stream>>>(qTbuf, kTbuf, attf);
        scoresW_kernel<<<dim3(HH, g), 256, 0, stream>>>(qbuf, kbuf, attf);
        int rows = g * PP;
        softmax192_kernel<<<dim3(rows / 4), 256, 0, stream>>>(attf, attb, rows);

        // examplar path
        gemm_conv<128, true><<<dim3(72, 4, g), 256, 0, stream>>>(Wvb, xTe, bv, vbuf, CP);
        transpose_hw_b<<<dim3(g * 512), 256, 0, stream>>>(vbuf, vTb);
        applyHT_b<<<dim3(WW, 8, g), 256, 0, stream>>>(vTb, attb, raw1);
        applyW_b<<<dim3(HH, 8, g), 256, 0, stream>>>(vbuf, attb, raw2);
        combine_b<<<dim3(g * 512), 256, 0, stream>>>(raw1, raw2, xe, g1, o0);

        // query path
        gemm_conv<128, true><<<dim3(72, 4, g), 256, 0, stream>>>(Wqvb, xTq, bqv, vbuf, CP);
        transpose_hw_b<<<dim3(g * 512), 256, 0, stream>>>(vbuf, vTb);
        applyHT_b<<<dim3(WW, 8, g), 256, 0, stream>>>(vTb, attb, raw1);
        applyW_b<<<dim3(HH, 8, g), 256, 0, stream>>>(vbuf, attb, raw2);
        combine_b<<<dim3(g * 512), 256, 0, stream>>>(raw1, raw2, xq, g2, o1);
    }
}

// Round 4
// 759.720 us; speedup vs baseline: 3.6622x; 1.4303x over previous
//
#include <hip/hip_runtime.h>
#include <math.h>

#define C_   512
#define C8_  64
#define HH   96
#define WW   96
#define PP   9216            // HH*WW
#define CP   4718592         // C_*PP
#define C8P  589824          // C8_*PP
#define ATTN 1769472         // PP*192

typedef __attribute__((ext_vector_type(4))) float f32x4;
typedef __attribute__((ext_vector_type(8))) __bf16 bf16x8;
typedef __attribute__((ext_vector_type(8))) unsigned short ushort8;

__device__ __forceinline__ float bf2f(unsigned short u) {
    union { unsigned u; float f; } x; x.u = ((unsigned)u) << 16; return x.f;
}
__device__ __forceinline__ unsigned short f2bf(float f) {
    union { float f; unsigned u; } x; x.f = f;
    unsigned r = x.u + 0x7fffu + ((x.u >> 16) & 1u);
    return (unsigned short)(r >> 16);
}
__device__ __forceinline__ void gload16(const void* g, void* l) {
    __builtin_amdgcn_global_load_lds(
        (const __attribute__((address_space(1))) unsigned int*)g,
        (__attribute__((address_space(3))) unsigned int*)l, 16, 0, 0);
}

// ---------------- weight cast fp32 -> bf16 (layout [O][C] kept) ----------------
__global__ __launch_bounds__(256) void cast_f32_bf16(
    const float* __restrict__ in, unsigned short* __restrict__ out, int n)
{
    int i = blockIdx.x * 256 + threadIdx.x;
    if (i < n) out[i] = f2bf(in[i]);
}

// ---------------- x [b][C][P] fp32 -> xT [b][P][C] bf16 ----------------
__global__ __launch_bounds__(256) void cast_transpose_cp(
    const float* __restrict__ x, unsigned short* __restrict__ xT)
{
    int p0 = blockIdx.x * 64, c0 = blockIdx.y * 64;
    size_t b = blockIdx.z;
    const float* xb = x + b * (size_t)CP;
    unsigned short* xTb = xT + b * (size_t)CP;
    __shared__ unsigned short T[64][65];
    int tid = threadIdx.x;
#pragma unroll
    for (int i = 0; i < 16; ++i) {
        int e = tid + 256 * i;
        int r = e >> 6, c = e & 63;
        T[r][c] = f2bf(xb[(size_t)(c0 + r) * PP + p0 + c]);
    }
    __syncthreads();
#pragma unroll
    for (int i = 0; i < 16; ++i) {
        int e = tid + 256 * i;
        int pr = e >> 6, cc = e & 63;
        xTb[(size_t)(p0 + pr) * C_ + c0 + cc] = T[cc][pr];
    }
}

// ---------------- MFMA GEMM: out[b,o,p] = bias[o] + sum_k W[o,k]*xT[b,p,k] ----------------
template<int BM, bool OUT_BF16>
__global__ __launch_bounds__(256) void gemm_conv(
    const unsigned short* __restrict__ A, const unsigned short* __restrict__ Bmat,
    const float* __restrict__ bias, void* __restrict__ outv, int OPP)
{
    constexpr int FM = BM / 32;
    int p0 = blockIdx.x * 128;
    int o0 = blockIdx.y * BM;
    size_t b = blockIdx.z;
    const unsigned short* Bb = Bmat + b * (size_t)CP;

    __shared__ __align__(16) unsigned short Asm[BM * 32];
    __shared__ __align__(16) unsigned short Bsm[128 * 32];

    int tid = threadIdx.x;
    int lane = tid & 63, wid = tid >> 6;
    int wr = wid >> 1, wc = wid & 1;
    int l15 = lane & 15, l4 = lane >> 4;

    f32x4 acc[FM][4] = {};

    for (int k0 = 0; k0 < 512; k0 += 32) {
        {
            int c = tid;
            gload16(A + (size_t)(o0 + (c >> 2)) * 512 + k0 + (c & 3) * 8, Asm + c * 8);
            if constexpr (BM == 128) {
                int ca = tid + 256;
                gload16(A + (size_t)(o0 + (ca >> 2)) * 512 + k0 + (ca & 3) * 8, Asm + ca * 8);
            }
            gload16(Bb + (size_t)(p0 + (c >> 2)) * 512 + k0 + (c & 3) * 8, Bsm + c * 8);
            int cb = tid + 256;
            gload16(Bb + (size_t)(p0 + (cb >> 2)) * 512 + k0 + (cb & 3) * 8, Bsm + cb * 8);
        }
        __syncthreads();
        bf16x8 af[FM], bfr[4];
#pragma unroll
        for (int m = 0; m < FM; ++m)
            af[m] = *(const bf16x8*)&Asm[(wr * (BM / 2) + m * 16 + l15) * 32 + l4 * 8];
#pragma unroll
        for (int n = 0; n < 4; ++n)
            bfr[n] = *(const bf16x8*)&Bsm[(wc * 64 + n * 16 + l15) * 32 + l4 * 8];
#pragma unroll
        for (int m = 0; m < FM; ++m)
#pragma unroll
            for (int n = 0; n < 4; ++n)
                acc[m][n] = __builtin_amdgcn_mfma_f32_16x16x32_bf16(af[m], bfr[n], acc[m][n], 0, 0, 0);
        __syncthreads();
    }

#pragma unroll
    for (int m = 0; m < FM; ++m) {
#pragma unroll
        for (int n = 0; n < 4; ++n) {
            int pcol = p0 + wc * 64 + n * 16 + l15;
#pragma unroll
            for (int r = 0; r < 4; ++r) {
                int orow = o0 + wr * (BM / 2) + m * 16 + l4 * 4 + r;
                float val = acc[m][n][r] + bias[orow];
                if constexpr (OUT_BF16)
                    ((unsigned short*)outv)[b * (size_t)OPP + (size_t)orow * PP + pcol] = f2bf(val);
                else
                    ((float*)outv)[b * (size_t)OPP + (size_t)orow * PP + pcol] = val;
            }
        }
    }
}

// ---------------- spatial transpose fp32: out[m,w,h] = in[m,h,w] ----------------
__global__ __launch_bounds__(256) void transpose_hw(
    const float* __restrict__ in, float* __restrict__ out)
{
    size_t m = blockIdx.x;
    const float* im = in + m * (size_t)PP;
    float* om = out + m * (size_t)PP;
    __shared__ float T[96][97];
    for (int idx = threadIdx.x; idx < PP; idx += 256) {
        int r = idx / 96, c = idx - r * 96;
        T[r][c] = im[idx];
    }
    __syncthreads();
    for (int idx = threadIdx.x; idx < PP; idx += 256) {
        int r = idx / 96, c = idx - r * 96;
        om[idx] = T[c][r];
    }
}

// ---------------- spatial transpose bf16 ----------------
__global__ __launch_bounds__(256) void transpose_hw_b(
    const unsigned short* __restrict__ in, unsigned short* __restrict__ out)
{
    size_t m = blockIdx.x;
    const unsigned short* im = in + m * (size_t)PP;
    unsigned short* om = out + m * (size_t)PP;
    __shared__ unsigned short T[96][97];
    for (int idx = threadIdx.x; idx < PP; idx += 256) {
        int r = idx / 96, c = idx - r * 96;
        T[r][c] = im[idx];
    }
    __syncthreads();
    for (int idx = threadIdx.x; idx < PP; idx += 256) {
        int r = idx / 96, c = idx - r * 96;
        om[idx] = T[c][r];
    }
}

// ---------------- scoresHT: att[b,h,w,j] = sum_c qT[c,w,h]*kT[c,w,j], mask j==h ----------------
__global__ __launch_bounds__(256) void scoresHT_kernel(
    const float* __restrict__ qT, const float* __restrict__ kT, float* __restrict__ att)
{
    int w = blockIdx.x;
    size_t b = blockIdx.y;
    const float* qb = qT + b * (size_t)C8P;
    const float* kb = kT + b * (size_t)C8P;
    float* attb = att + b * (size_t)ATTN;
    __shared__ float Qs[64][96];
    __shared__ float Ks[64][96];
    for (int idx = threadIdx.x; idx < 64 * 96; idx += 256) {
        int c = idx / 96, h = idx - c * 96;
        size_t gidx = (size_t)c * PP + (size_t)w * 96 + h;
        Qs[c][h] = qb[gidx];
        Ks[c][h] = kb[gidx];
    }
    __syncthreads();
    int tx = threadIdx.x & 15, ty = threadIdx.x >> 4;
    float acc[6][6] = {};
    for (int c = 0; c < 64; ++c) {
        float qf[6], kf[6];
#pragma unroll
        for (int i = 0; i < 6; ++i) { qf[i] = Qs[c][ty + 16 * i]; kf[i] = Ks[c][tx + 16 * i]; }
#pragma unroll
        for (int i = 0; i < 6; ++i)
#pragma unroll
            for (int j = 0; j < 6; ++j) acc[i][j] = fmaf(qf[i], kf[j], acc[i][j]);
    }
#pragma unroll
    for (int i = 0; i < 6; ++i) {
        int h = ty + 16 * i;
#pragma unroll
        for (int j = 0; j < 6; ++j) {
            int jj = tx + 16 * j;
            attb[((size_t)h * 96 + w) * 192 + jj] = (jj == h) ? -INFINITY : acc[i][j];
        }
    }
}

// ---------------- scoresW: att[b,h,w,96+j] = sum_c q[c,h,w]*k[c,h,j] ----------------
__global__ __launch_bounds__(256) void scoresW_kernel(
    const float* __restrict__ q, const float* __restrict__ k, float* __restrict__ att)
{
    int h = blockIdx.x;
    size_t b = blockIdx.y;
    const float* qb = q + b * (size_t)C8P;
    const float* kb = k + b * (size_t)C8P;
    float* attb = att + b * (size_t)ATTN;
    __shared__ float Qs[64][96];
    __shared__ float Ks[64][96];
    for (int idx = threadIdx.x; idx < 64 * 96; idx += 256) {
        int c = idx / 96, w = idx - c * 96;
        size_t gidx = (size_t)c * PP + (size_t)h * 96 + w;
        Qs[c][w] = qb[gidx];
        Ks[c][w] = kb[gidx];
    }
    __syncthreads();
    int tx = threadIdx.x & 15, ty = threadIdx.x >> 4;
    float acc[6][6] = {};
    for (int c = 0; c < 64; ++c) {
        float qf[6], kf[6];
#pragma unroll
        for (int i = 0; i < 6; ++i) { qf[i] = Qs[c][ty + 16 * i]; kf[i] = Ks[c][tx + 16 * i]; }
#pragma unroll
        for (int i = 0; i < 6; ++i)
#pragma unroll
            for (int j = 0; j < 6; ++j) acc[i][j] = fmaf(qf[i], kf[j], acc[i][j]);
    }
#pragma unroll
    for (int i = 0; i < 6; ++i) {
        int w = ty + 16 * i;
#pragma unroll
        for (int j = 0; j < 6; ++j) {
            int jj = tx + 16 * j;
            attb[((size_t)h * 96 + w) * 192 + 96 + jj] = acc[i][j];
        }
    }
}

// ---------------- softmax over 192 fp32 -> bf16 probs ----------------
__global__ __launch_bounds__(256) void softmax192_kernel(
    const float* __restrict__ att, unsigned short* __restrict__ attb, int nrows)
{
    int row = blockIdx.x * 4 + (threadIdx.x >> 6);
    int lane = threadIdx.x & 63;
    if (row >= nrows) return;
    const float* r = att + (size_t)row * 192;
    unsigned short* o = attb + (size_t)row * 192;
    float v0 = r[lane], v1 = r[lane + 64], v2 = r[lane + 128];
    float m = fmaxf(fmaxf(v0, v1), v2);
#pragma unroll
    for (int off = 32; off; off >>= 1) m = fmaxf(m, __shfl_xor(m, off));
    float e0 = __expf(v0 - m), e1 = __expf(v1 - m), e2 = __expf(v2 - m);
    float s = e0 + e1 + e2;
#pragma unroll
    for (int off = 32; off; off >>= 1) s += __shfl_xor(s, off);
    float inv = 1.0f / s;
    o[lane] = f2bf(e0 * inv); o[lane + 64] = f2bf(e1 * inv); o[lane + 128] = f2bf(e2 * inv);
}

// ---------------- MFMA apply ----------------
// HT=true : raw[b,c,w,h] = sum_j att[b,h,w,j]   * vT[b,c,w,j]   (s = w, col = h)
// HT=false: raw[b,c,h,w] = sum_j att[b,h,w,96+j]* v [b,c,h,j]   (s = h, col = w)
// grid (96, 2, g), 512 threads = 8 waves (4 c-rows x 2 col-halves). Tile 256c x 96col, K=96.
template<bool HT>
__global__ __launch_bounds__(512) void apply_mfma(
    const unsigned short* __restrict__ V, const unsigned short* __restrict__ att,
    unsigned short* __restrict__ outb)
{
    int s = blockIdx.x;
    int c0 = blockIdx.y * 256;
    size_t b = blockIdx.z;
    const unsigned short* vb = V + b * (size_t)CP;
    const unsigned short* ab = att + b * (size_t)ATTN;
    unsigned short* ob = outb + b * (size_t)CP;

    __shared__ __align__(16) unsigned short Asm[256][104];  // [c][j] pad->104 (16B rows, 2-way banks)
    __shared__ __align__(16) unsigned short Bsm[96][104];   // [col][j]

    int tid = threadIdx.x;
    {
        int r = tid >> 1, half = tid & 1;
        const unsigned short* src = vb + (size_t)(c0 + r) * PP + s * 96 + half * 48;
#pragma unroll
        for (int i = 0; i < 6; ++i)
            *(ushort8*)&Asm[r][half * 48 + i * 8] = *(const ushort8*)(src + i * 8);
    }
    if (tid < 192) {
        int r = tid >> 1, half = tid & 1;
        size_t base = HT ? ((size_t)(r * 96 + s) * 192)
                         : ((size_t)(s * 96 + r) * 192 + 96);
        const unsigned short* src = ab + base + half * 48;
#pragma unroll
        for (int i = 0; i < 6; ++i)
            *(ushort8*)&Bsm[r][half * 48 + i * 8] = *(const ushort8*)(src + i * 8);
    }
    __syncthreads();

    int lane = tid & 63, wid = tid >> 6;
    int wr = wid >> 1, wc = wid & 1;
    int l15 = lane & 15, l4 = lane >> 4;
    f32x4 acc[4][3] = {};
#pragma unroll
    for (int k = 0; k < 3; ++k) {
        bf16x8 a[4], bb[3];
#pragma unroll
        for (int m = 0; m < 4; ++m)
            a[m] = *(const bf16x8*)&Asm[wr * 64 + m * 16 + l15][k * 32 + l4 * 8];
#pragma unroll
        for (int n = 0; n < 3; ++n)
            bb[n] = *(const bf16x8*)&Bsm[wc * 48 + n * 16 + l15][k * 32 + l4 * 8];
#pragma unroll
        for (int m = 0; m < 4; ++m)
#pragma unroll
            for (int n = 0; n < 3; ++n)
                acc[m][n] = __builtin_amdgcn_mfma_f32_16x16x32_bf16(a[m], bb[n], acc[m][n], 0, 0, 0);
    }
#pragma unroll
    for (int m = 0; m < 4; ++m)
#pragma unroll
        for (int n = 0; n < 3; ++n) {
            int col = wc * 48 + n * 16 + l15;
#pragma unroll
            for (int r = 0; r < 4; ++r) {
                int crow = c0 + wr * 64 + m * 16 + l4 * 4 + r;
                ob[(size_t)crow * PP + s * 96 + col] = f2bf(acc[m][n][r]);
            }
        }
}

// ---------------- combine: out[c,h,w] = g*(rawHT[c,w,h] + rawW[c,h,w] + 2) + x[c,h,w] ----------------
__global__ __launch_bounds__(256) void combine_b(
    const unsigned short* __restrict__ rawHT, const unsigned short* __restrict__ rawW,
    const float* __restrict__ x, const float* __restrict__ gamma,
    float* __restrict__ out)
{
    size_t m = blockIdx.x;
    const unsigned short* a  = rawHT + m * (size_t)PP;
    const unsigned short* bw = rawW  + m * (size_t)PP;
    const float* xm = x + m * (size_t)PP;
    float* om = out + m * (size_t)PP;
    float g = gamma[0];
    __shared__ float T[96][97];
    for (int idx = threadIdx.x; idx < PP; idx += 256) {
        int r = idx / 96, c = idx - r * 96;
        T[r][c] = bf2f(a[idx]);
    }
    __syncthreads();
    for (int idx = threadIdx.x; idx < PP; idx += 256) {
        int r = idx / 96, c = idx - r * 96;   // r = h, c = w
        om[idx] = g * (T[c][r] + bf2f(bw[idx]) + 2.0f) + xm[idx];
    }
}

extern "C" void kernel_launch(void* const* d_in, const int* in_sizes, int n_in,
                              void* d_out, int out_size, void* d_ws, size_t ws_size,
                              hipStream_t stream)
{
    const float* x_ex = (const float*)d_in[0];
    const float* x_q  = (const float*)d_in[1];
    const float* Wq   = (const float*)d_in[2];
    const float* bq   = (const float*)d_in[3];
    const float* Wk   = (const float*)d_in[4];
    const float* bk   = (const float*)d_in[5];
    const float* Wv   = (const float*)d_in[6];
    const float* bv   = (const float*)d_in[7];
    const float* Wqv  = (const float*)d_in[8];
    const float* bqv  = (const float*)d_in[9];
    const float* g1   = (const float*)d_in[10];
    const float* g2   = (const float*)d_in[11];
    float* out0 = (float*)d_out;
    float* out1 = out0 + (size_t)8 * CP;

    char* p = (char*)d_ws;
    unsigned short* Wvb  = (unsigned short*)p; p += (size_t)262144 * 2;
    unsigned short* Wqvb = (unsigned short*)p; p += (size_t)262144 * 2;
    unsigned short* Wqb  = (unsigned short*)p; p += (size_t)32768 * 2;
    unsigned short* Wkb  = (unsigned short*)p; p += (size_t)32768 * 2;

    size_t per = (size_t)ATTN * 4 + (size_t)ATTN * 2 + 6ull * CP * 2 + 4ull * C8P * 4;
    size_t head = (size_t)(p - (char*)d_ws);
    int g = 8;
    while (g > 1 && head + (size_t)g * per > ws_size) g >>= 1;

    char* q = p;
    float*          attf = (float*)q;          q += (size_t)g * ATTN * 4;
    unsigned short* attb = (unsigned short*)q; q += (size_t)g * ATTN * 2;
    unsigned short* xTe  = (unsigned short*)q; q += (size_t)g * CP * 2;
    unsigned short* xTq  = (unsigned short*)q; q += (size_t)g * CP * 2;
    unsigned short* vbuf = (unsigned short*)q; q += (size_t)g * CP * 2;
    unsigned short* vTb  = (unsigned short*)q; q += (size_t)g * CP * 2;
    unsigned short* raw1 = (unsigned short*)q; q += (size_t)g * CP * 2;
    unsigned short* raw2 = (unsigned short*)q; q += (size_t)g * CP * 2;
    float* qbuf  = (float*)q; q += (size_t)g * C8P * 4;
    float* kbuf  = (float*)q; q += (size_t)g * C8P * 4;
    float* qTbuf = (float*)q; q += (size_t)g * C8P * 4;
    float* kTbuf = (float*)q; q += (size_t)g * C8P * 4;

    cast_f32_bf16<<<dim3(1024), 256, 0, stream>>>(Wv,  Wvb,  262144);
    cast_f32_bf16<<<dim3(1024), 256, 0, stream>>>(Wqv, Wqvb, 262144);
    cast_f32_bf16<<<dim3(128),  256, 0, stream>>>(Wq,  Wqb,  32768);
    cast_f32_bf16<<<dim3(128),  256, 0, stream>>>(Wk,  Wkb,  32768);

    for (int b0 = 0; b0 < 8; b0 += g) {
        const float* xe = x_ex + (size_t)b0 * CP;
        const float* xq = x_q  + (size_t)b0 * CP;
        float* o0 = out0 + (size_t)b0 * CP;
        float* o1 = out1 + (size_t)b0 * CP;

        cast_transpose_cp<<<dim3(144, 8, g), 256, 0, stream>>>(xq, xTq);
        cast_transpose_cp<<<dim3(144, 8, g), 256, 0, stream>>>(xe, xTe);

        gemm_conv<64, false><<<dim3(72, 1, g), 256, 0, stream>>>(Wqb, xTq, bq, qbuf, C8P);
        gemm_conv<64, false><<<dim3(72, 1, g), 256, 0, stream>>>(Wkb, xTe, bk, kbuf, C8P);
        transpose_hw<<<dim3(g * 64), 256, 0, stream>>>(qbuf, qTbuf);
        transpose_hw<<<dim3(g * 64), 256, 0, stream>>>(kbuf, kTbuf);

        scoresHT_kernel<<<dim3(WW, g), 256, 0, stream>>>(qTbuf, kTbuf, attf);
        scoresW_kernel<<<dim3(HH, g), 256, 0, stream>>>(qbuf, kbuf, attf);
        int rows = g * PP;
        softmax192_kernel<<<dim3(rows / 4), 256, 0, stream>>>(attf, attb, rows);

        // examplar path
        gemm_conv<128, true><<<dim3(72, 4, g), 256, 0, stream>>>(Wvb, xTe, bv, vbuf, CP);
        transpose_hw_b<<<dim3(g * 512), 256, 0, stream>>>(vbuf, vTb);
        apply_mfma<true><<<dim3(96, 2, g), 512, 0, stream>>>(vTb, attb, raw1);
        apply_mfma<false><<<dim3(96, 2, g), 512, 0, stream>>>(vbuf, attb, raw2);
        combine_b<<<dim3(g * 512), 256, 0, stream>>>(raw1, raw2, xe, g1, o0);

        // query path
        gemm_conv<128, true><<<dim3(72, 4, g), 256, 0, stream>>>(Wqvb, xTq, bqv, vbuf, CP);
        transpose_hw_b<<<dim3(g * 512), 256, 0, stream>>>(vbuf, vTb);
        apply_mfma<true><<<dim3(96, 2, g), 512, 0, stream>>>(vTb, attb, raw1);
        apply_mfma<false><<<dim3(96, 2, g), 512, 0, stream>>>(vbuf, attb, raw2);
        combine_b<<<dim3(g * 512), 256, 0, stream>>>(raw1, raw2, xq, g2, o1);
    }
}